// Round 2
// baseline (344.322 us; speedup 1.0000x reference)
//
#include <hip/hip_runtime.h>
#include <hip/hip_bf16.h>
#include <stdint.h>

#define IN_F   4096
#define OUT_F  768
#define OUTB   (OUT_F * 8)       // 6144
#define BATCH  1024
#define SPLITK 4
#define KSPAN  (IN_F / SPLITK)   // 1024
#define BK     64
#define NIT    (KSPAN / BK)      // 16
#define PLANE  (BATCH * OUT_F)   // 786432 floats
#define PLANE4 (PLANE / 4)       // 196608 float4
#define NTILE  192               // 12 x 16 output tiles

// ws layout (bytes):
//   0        : predp   float[4][PLANE]     split-K partial planes (12.58 MB)
//   12582912 : wp      ushort[IN_F*OUT_F]  packed [(k/8)][n][k%8]  (6.29 MB)
//   18874368 : labf    ushort[BATCH*IN_F]  bf16 latent row-major   (8.39 MB)
//   27262976 : regpart float[1536]
//   27269120 : tiletick u32[192]           per-tile split-K tickets
//   27269888 : ctrl    {float sqsum; u32 gticket}
#define WS_WP    12582912
#define WS_LABF  18874368
#define WS_REGP  27262976
#define WS_TICK  27269120
#define WS_CTRL  27269888

typedef short short8  __attribute__((ext_vector_type(8)));
typedef float f32x4   __attribute__((ext_vector_type(4)));
typedef unsigned int u32;

__device__ __forceinline__ ushort f2bf(float f) {
    uint32_t u = __builtin_bit_cast(uint32_t, f);
    u += 0x7FFFu + ((u >> 16) & 1u);
    return (ushort)(u >> 16);
}

__device__ __forceinline__ float waveReduceSum(float v) {
    #pragma unroll
    for (int off = 32; off > 0; off >>= 1) v += __shfl_down(v, off, 64);
    return v;
}

__device__ __forceinline__ void glds16(const void* g, void* l) {
    __builtin_amdgcn_global_load_lds(
        (const __attribute__((address_space(1))) u32*)g,
        (__attribute__((address_space(3))) u32*)l, 16, 0, 0);
}

// k_weights: blocks [0,1536): int_weights (bf16 packed [(k/8)][n][k%8]) + reg
// partials. blocks [1536,2048): latent fp32->bf16 conversion. Block 0 also
// zero-inits tile tickets + ctrl (workspace is poisoned between iterations).
__global__ __launch_bounds__(256) void k_weights(const float* __restrict__ w,
                                                 const float* __restrict__ latent,
                                                 ushort* __restrict__ wp,
                                                 ushort* __restrict__ labf,
                                                 float* __restrict__ regpart,
                                                 u32* __restrict__ tiletick,
                                                 float* __restrict__ ctrl) {
    if (blockIdx.x == 0) {
        if (threadIdx.x < NTILE) tiletick[threadIdx.x] = 0u;
        if (threadIdx.x == NTILE)     ctrl[0] = 0.f;          // sqsum
        if (threadIdx.x == NTILE + 1) ((u32*)ctrl)[1] = 0u;   // gticket
    }
    if (blockIdx.x >= 1536) {
        int t = (blockIdx.x - 1536) * 256 + threadIdx.x;
        const float4* src = (const float4*)latent;
        uint4* dst = (uint4*)labf;
        #pragma unroll
        for (int j = 0; j < 4; j++) {
            int o = j * 131072 + t;
            float4 a0 = src[2 * o];
            float4 a1 = src[2 * o + 1];
            union { ushort u[8]; uint4 v; } pk;
            pk.u[0] = f2bf(a0.x); pk.u[1] = f2bf(a0.y); pk.u[2] = f2bf(a0.z); pk.u[3] = f2bf(a0.w);
            pk.u[4] = f2bf(a1.x); pk.u[5] = f2bf(a1.y); pk.u[6] = f2bf(a1.z); pk.u[7] = f2bf(a1.w);
            dst[o] = pk.v;
        }
        return;
    }

    int t  = blockIdx.x * 256 + threadIdx.x;
    int o  = t % OUT_F;
    int i8 = t / OUT_F;
    const float* src = w + (size_t)(i8 * 8) * OUTB + (size_t)o * 8;

    const float P[8] = {1.f, 2.f, 4.f, 8.f, 16.f, 32.f, 64.f, -128.f};
    float regsum = 0.f;
    union { ushort u[8]; uint4 v; } pk;

    #pragma unroll
    for (int r = 0; r < 8; r++) {
        float4 a = *(const float4*)(src + (size_t)r * OUTB);
        float4 b = *(const float4*)(src + (size_t)r * OUTB + 4);
        float x[8] = {a.x, a.y, a.z, a.w, b.x, b.y, b.z, b.w};
        float iw = 0.f;
        #pragma unroll
        for (int j = 0; j < 8; j++) {
            float p = __builtin_amdgcn_rcpf(1.f + __expf(-x[j]));
            iw += p * P[j];
            regsum += fminf(p, 1.f - p);
        }
        pk.u[r] = f2bf(iw);
    }
    *(uint4*)(wp + ((size_t)i8 * OUT_F + o) * 8) = pk.v;

    float ws = waveReduceSum(regsum);
    __shared__ float red[4];
    int lane = threadIdx.x & 63, wv = threadIdx.x >> 6;
    if (lane == 0) red[wv] = ws;
    __syncthreads();
    if (threadIdx.x == 0) regpart[blockIdx.x] = red[0] + red[1] + red[2] + red[3];
}

// k_gemm_epi: split-K=4 bf16 MFMA GEMM (64x64 tile, BK=64, double-buffered,
// B staged via global_load_lds; 768 blocks = 3/CU co-resident). Partial planes
// are plain disjoint stores; the 4th split-K arriver per tile (per-tile
// ACQ_REL ticket) fuses the squared-error epilogue vs tsum; a global ticket
// elects one block to fold regpart and write the 3 outputs.
__global__ __launch_bounds__(256) void k_gemm_epi(const ushort* __restrict__ labf,
                                                  const ushort* __restrict__ wp,
                                                  const float* __restrict__ tsum,
                                                  const float* __restrict__ regpart,
                                                  float* __restrict__ predp,
                                                  u32* __restrict__ tiletick,
                                                  float* __restrict__ ctrl,
                                                  float* __restrict__ out) {
    __shared__ __align__(16) ushort lA[2][64 * 72];   // row stride 72
    __shared__ __align__(16) ushort lB[2][8 * 1032];  // plane stride 1032
    __shared__ float red[4];
    __shared__ int lastf;

    const int tid  = threadIdx.x;
    const int n0   = blockIdx.x * 64;
    const int m0   = blockIdx.y * 64;
    const int bz   = blockIdx.z;
    const int kbase = bz * KSPAN;
    const int kg0   = kbase >> 3;
    const int lane = tid & 63, w = tid >> 6;
    const int wm = w >> 1, wn = w & 1;
    const int quad = lane >> 4, l16 = lane & 15;

    f32x4 acc[2][2] = {{{0.f,0.f,0.f,0.f},{0.f,0.f,0.f,0.f}},
                       {{0.f,0.f,0.f,0.f},{0.f,0.f,0.f,0.f}}};

    const int ar = tid >> 2, ac = tid & 3;            // A: row, 16-elem k-chunk
    const ushort* aptr = labf + (size_t)(m0 + ar) * IN_F + kbase + ac * 16;
    const ushort* bbase = wp + ((size_t)kg0 * OUT_F + n0 + lane) * 8;

    int buf = 0;
    glds16(bbase + (size_t)(2 * w) * OUT_F * 8,     &lB[0][(2 * w) * 1032]);
    glds16(bbase + (size_t)(2 * w + 1) * OUT_F * 8, &lB[0][(2 * w + 1) * 1032]);
    {
        uint4 a0 = *(const uint4*)aptr;
        uint4 a1 = *(const uint4*)(aptr + 8);
        *(uint4*)&lA[0][ar * 72 + ac * 16]     = a0;
        *(uint4*)&lA[0][ar * 72 + ac * 16 + 8] = a1;
    }
    __syncthreads();

    for (int it = 0; it < NIT; ++it) {
        const int nxt = buf ^ 1;
        uint4 a0, a1;
        if (it + 1 < NIT) {
            const ushort* bp = bbase + (size_t)(it + 1) * 8 * OUT_F * 8;
            glds16(bp + (size_t)(2 * w) * OUT_F * 8,     &lB[nxt][(2 * w) * 1032]);
            glds16(bp + (size_t)(2 * w + 1) * OUT_F * 8, &lB[nxt][(2 * w + 1) * 1032]);
            a0 = *(const uint4*)(aptr + (it + 1) * BK);
            a1 = *(const uint4*)(aptr + (it + 1) * BK + 8);
        }
        #pragma unroll
        for (int s = 0; s < 2; ++s) {
            short8 af0 = *(short8*)&lA[buf][(wm * 32 + l16) * 72 + s * 32 + quad * 8];
            short8 af1 = *(short8*)&lA[buf][(wm * 32 + 16 + l16) * 72 + s * 32 + quad * 8];
            short8 bf0 = *(short8*)&lB[buf][(s * 4 + quad) * 1032 + (wn * 32 + l16) * 8];
            short8 bf1 = *(short8*)&lB[buf][(s * 4 + quad) * 1032 + (wn * 32 + 16 + l16) * 8];
            acc[0][0] = __builtin_amdgcn_mfma_f32_16x16x32_bf16(af0, bf0, acc[0][0], 0, 0, 0);
            acc[0][1] = __builtin_amdgcn_mfma_f32_16x16x32_bf16(af0, bf1, acc[0][1], 0, 0, 0);
            acc[1][0] = __builtin_amdgcn_mfma_f32_16x16x32_bf16(af1, bf0, acc[1][0], 0, 0, 0);
            acc[1][1] = __builtin_amdgcn_mfma_f32_16x16x32_bf16(af1, bf1, acc[1][1], 0, 0, 0);
        }
        if (it + 1 < NIT) {
            *(uint4*)&lA[nxt][ar * 72 + ac * 16]     = a0;
            *(uint4*)&lA[nxt][ar * 72 + ac * 16 + 8] = a1;
        }
        __syncthreads();
        buf = nxt;
    }

    // store this split-K partial plane (disjoint plain stores)
    float* plane = predp + (size_t)bz * PLANE;
    #pragma unroll
    for (int fm = 0; fm < 2; fm++)
    #pragma unroll
    for (int fn = 0; fn < 2; fn++)
    #pragma unroll
    for (int r = 0; r < 4; r++) {
        int m = m0 + wm * 32 + fm * 16 + quad * 4 + r;
        int n = n0 + wn * 32 + fn * 16 + l16;
        plane[(size_t)m * OUT_F + n] = acc[fm][fn][r];
    }

    // ---- per-tile split-K ticket: 4th arriver runs the fused epilogue ----
    __threadfence();
    __syncthreads();                 // all stores in this block issued
    const int tile_id = blockIdx.y * 12 + blockIdx.x;
    u32 told = 0;
    if (tid == 0) {
        told = __hip_atomic_fetch_add(&tiletick[tile_id], 1u,
                                      __ATOMIC_ACQ_REL, __HIP_MEMORY_SCOPE_AGENT);
        lastf = (told == (u32)(SPLITK - 1));
    }
    __syncthreads();
    if (!lastf) return;
    __threadfence();                 // acquire: other planes' stores visible

    // epilogue over this 64x64 tile: sum (pred - isum)^2
    const int r16 = tid >> 4, c16 = tid & 15;
    const float4* pp = (const float4*)predp;
    float lsum = 0.f;
    #pragma unroll
    for (int j = 0; j < 4; j++) {
        int m = m0 + j * 16 + r16;
        int n = n0 + c16 * 4;
        int g = (m * OUT_F + n) >> 2;
        float4 p0 = pp[g];
        float4 p1 = pp[g + PLANE4];
        float4 p2 = pp[g + 2 * PLANE4];
        float4 p3 = pp[g + 3 * PLANE4];
        float pv[4] = {p0.x + p1.x + p2.x + p3.x, p0.y + p1.y + p2.y + p3.y,
                       p0.z + p1.z + p2.z + p3.z, p0.w + p1.w + p2.w + p3.w};
        const float* ts = tsum + (size_t)m * OUTB + (size_t)n * 8;
        #pragma unroll
        for (int q = 0; q < 4; q++) {
            float4 t0 = *(const float4*)(ts + q * 8);
            float4 t1 = *(const float4*)(ts + q * 8 + 4);
            float isum = t0.x + 2.f * t0.y + 4.f * t0.z + 8.f * t0.w
                       + 16.f * t1.x + 32.f * t1.y + 64.f * t1.z - 128.f * t1.w;
            float d = pv[q] - isum;
            lsum += d * d;
        }
    }
    float wsum = waveReduceSum(lsum);
    const int wv = tid >> 6;
    if ((tid & 63) == 0) red[wv] = wsum;
    __syncthreads();
    if (tid == 0) {
        float bsum = red[0] + red[1] + red[2] + red[3];
        atomicAdd(&ctrl[0], bsum);
        __threadfence();
        u32 gold = __hip_atomic_fetch_add(&((u32*)ctrl)[1], 1u,
                                          __ATOMIC_ACQ_REL, __HIP_MEMORY_SCOPE_AGENT);
        lastf = (gold == (u32)(NTILE - 1));
    }
    __syncthreads();

    if (lastf) {   // globally last tile: fold regpart + finalize outputs
        __threadfence();
        float r = 0.f;
        #pragma unroll
        for (int j = 0; j < 6; j++) r += regpart[tid + j * 256];
        r = waveReduceSum(r);
        __syncthreads();            // red[] reuse
        if ((tid & 63) == 0) red[wv] = r;
        __syncthreads();
        if (tid == 0) {
            float S = atomicAdd(&ctrl[0], 0.0f);   // coherent read of final sum
            float R = red[0] + red[1] + red[2] + red[3];
            float recon = S / ((float)(BATCH * OUT_F) * 255.f * 255.f);
            float reg   = 0.001f * R / (float)((size_t)IN_F * OUTB);
            out[0] = recon + reg;
            out[1] = recon;
            out[2] = reg;
        }
    }
}

extern "C" void kernel_launch(void* const* d_in, const int* in_sizes, int n_in,
                              void* d_out, int out_size, void* d_ws, size_t ws_size,
                              hipStream_t stream) {
    const float* latent = (const float*)d_in[0];   // [1024, 4096]
    const float* tsum   = (const float*)d_in[1];   // [1024, 6144]
    const float* weight = (const float*)d_in[2];   // [4096, 6144]
    float* out      = (float*)d_out;
    float* predp    = (float*)d_ws;
    ushort* wp      = (ushort*)((char*)d_ws + WS_WP);
    ushort* labf    = (ushort*)((char*)d_ws + WS_LABF);
    float* regpart  = (float*)((char*)d_ws + WS_REGP);
    u32*   tiletick = (u32*)((char*)d_ws + WS_TICK);
    float* ctrl     = (float*)((char*)d_ws + WS_CTRL);

    k_weights<<<2048, 256, 0, stream>>>(weight, latent, wp, labf, regpart, tiletick, ctrl);
    k_gemm_epi<<<dim3(OUT_F / 64, BATCH / 64, SPLITK), 256, 0, stream>>>(
        labf, wp, tsum, regpart, predp, tiletick, ctrl, out);
}

// Round 3
// 231.468 us; speedup vs baseline: 1.4876x; 1.4876x over previous
//
#include <hip/hip_runtime.h>
#include <hip/hip_bf16.h>
#include <stdint.h>

#define IN_F   4096
#define OUT_F  768
#define OUTB   (OUT_F * 8)       // 6144
#define BATCH  1024
#define SPLITK 8
#define KSPAN  (IN_F / SPLITK)   // 512
#define BK     64
#define NIT    (KSPAN / BK)      // 8
#define PLANE  (BATCH * OUT_F)   // 786432 floats
#define PLANE4 (PLANE / 4)       // 196608 float4
#define EPIBLK 768

// ws layout (bytes):
//   0        : predp   float[8][PLANE]     split-K partial planes (25.17 MB)
//   25165824 : wp      ushort[IN_F*OUT_F]  packed [(k/8)][n][k%8]  (6.29 MB)
//   31457280 : labf    ushort[BATCH*IN_F]  bf16 latent row-major   (8.39 MB)
//   39845888 : regpart float[1536]
//   39852032 : ctrl    {float sqsum; u32 ticket}   (zeroed by k_weights)
#define WS_WP    25165824
#define WS_LABF  31457280
#define WS_REGP  39845888
#define WS_CTRL  39852032

typedef short short8  __attribute__((ext_vector_type(8)));
typedef float f32x4   __attribute__((ext_vector_type(4)));
typedef unsigned int u32;

__device__ __forceinline__ ushort f2bf(float f) {
    uint32_t u = __builtin_bit_cast(uint32_t, f);
    u += 0x7FFFu + ((u >> 16) & 1u);
    return (ushort)(u >> 16);
}

__device__ __forceinline__ float waveReduceSum(float v) {
    #pragma unroll
    for (int off = 32; off > 0; off >>= 1) v += __shfl_down(v, off, 64);
    return v;
}

__device__ __forceinline__ void glds16(const void* g, void* l) {
    __builtin_amdgcn_global_load_lds(
        (const __attribute__((address_space(1))) u32*)g,
        (__attribute__((address_space(3))) u32*)l, 16, 0, 0);
}

// k_weights: blocks [0,1536): int_weights (bf16 packed [(k/8)][n][k%8]) + reg
// partials. blocks [1536,2048): latent fp32->bf16 conversion. Block 0 also
// zero-inits ctrl (workspace is poisoned between iterations).
__global__ __launch_bounds__(256) void k_weights(const float* __restrict__ w,
                                                 const float* __restrict__ latent,
                                                 ushort* __restrict__ wp,
                                                 ushort* __restrict__ labf,
                                                 float* __restrict__ regpart,
                                                 float* __restrict__ ctrl) {
    if (blockIdx.x == 0 && threadIdx.x == 0) {
        ctrl[0] = 0.f;                 // sqsum
        ((u32*)ctrl)[1] = 0u;          // ticket
    }
    if (blockIdx.x >= 1536) {
        int t = (blockIdx.x - 1536) * 256 + threadIdx.x;
        const float4* src = (const float4*)latent;
        uint4* dst = (uint4*)labf;
        #pragma unroll
        for (int j = 0; j < 4; j++) {
            int o = j * 131072 + t;
            float4 a0 = src[2 * o];
            float4 a1 = src[2 * o + 1];
            union { ushort u[8]; uint4 v; } pk;
            pk.u[0] = f2bf(a0.x); pk.u[1] = f2bf(a0.y); pk.u[2] = f2bf(a0.z); pk.u[3] = f2bf(a0.w);
            pk.u[4] = f2bf(a1.x); pk.u[5] = f2bf(a1.y); pk.u[6] = f2bf(a1.z); pk.u[7] = f2bf(a1.w);
            dst[o] = pk.v;
        }
        return;
    }

    int t  = blockIdx.x * 256 + threadIdx.x;
    int o  = t % OUT_F;
    int i8 = t / OUT_F;
    const float* src = w + (size_t)(i8 * 8) * OUTB + (size_t)o * 8;

    const float P[8] = {1.f, 2.f, 4.f, 8.f, 16.f, 32.f, 64.f, -128.f};
    float regsum = 0.f;
    union { ushort u[8]; uint4 v; } pk;

    #pragma unroll
    for (int r = 0; r < 8; r++) {
        float4 a = *(const float4*)(src + (size_t)r * OUTB);
        float4 b = *(const float4*)(src + (size_t)r * OUTB + 4);
        float x[8] = {a.x, a.y, a.z, a.w, b.x, b.y, b.z, b.w};
        float iw = 0.f;
        #pragma unroll
        for (int j = 0; j < 8; j++) {
            float p = __builtin_amdgcn_rcpf(1.f + __expf(-x[j]));
            iw += p * P[j];
            regsum += fminf(p, 1.f - p);
        }
        pk.u[r] = f2bf(iw);
    }
    *(uint4*)(wp + ((size_t)i8 * OUT_F + o) * 8) = pk.v;

    float ws = waveReduceSum(regsum);
    __shared__ float red[4];
    int lane = threadIdx.x & 63, wv = threadIdx.x >> 6;
    if (lane == 0) red[wv] = ws;
    __syncthreads();
    if (threadIdx.x == 0) regpart[blockIdx.x] = red[0] + red[1] + red[2] + red[3];
}

// k_gemm: split-K=8 bf16 MFMA GEMM, 128x64 tile (wave owns 32x64 -> 16 MFMA
// per K-step), BK=64, double-buffered, B via global_load_lds. Grid 12x8x8 =
// 768 blocks, 2 blocks/CU resident. Pure disjoint plane stores — NO fences.
__global__ __launch_bounds__(256) void k_gemm(const ushort* __restrict__ labf,
                                              const ushort* __restrict__ wp,
                                              float* __restrict__ predp) {
    __shared__ __align__(16) ushort lA[2][128 * 72];  // row stride 72
    __shared__ __align__(16) ushort lB[2][8 * 1032];  // plane stride 1032

    const int tid  = threadIdx.x;
    const int n0   = blockIdx.x * 64;
    const int m0   = blockIdx.y * 128;
    const int bz   = blockIdx.z;
    const int kbase = bz * KSPAN;
    const int kg0   = kbase >> 3;
    const int lane = tid & 63, w = tid >> 6;
    const int quad = lane >> 4, l16 = lane & 15;

    f32x4 acc[2][4] = {{{0.f,0.f,0.f,0.f},{0.f,0.f,0.f,0.f},{0.f,0.f,0.f,0.f},{0.f,0.f,0.f,0.f}},
                       {{0.f,0.f,0.f,0.f},{0.f,0.f,0.f,0.f},{0.f,0.f,0.f,0.f},{0.f,0.f,0.f,0.f}}};

    const int ar = tid >> 1, ac = tid & 1;            // A: row, 32-elem half
    const ushort* aptr = labf + (size_t)(m0 + ar) * IN_F + kbase + ac * 32;
    const ushort* bbase = wp + ((size_t)kg0 * OUT_F + n0 + lane) * 8;

    int buf = 0;
    glds16(bbase + (size_t)(2 * w) * OUT_F * 8,     &lB[0][(2 * w) * 1032]);
    glds16(bbase + (size_t)(2 * w + 1) * OUT_F * 8, &lB[0][(2 * w + 1) * 1032]);
    {
        uint4 a0 = *(const uint4*)aptr;
        uint4 a1 = *(const uint4*)(aptr + 8);
        uint4 a2 = *(const uint4*)(aptr + 16);
        uint4 a3 = *(const uint4*)(aptr + 24);
        *(uint4*)&lA[0][ar * 72 + ac * 32]      = a0;
        *(uint4*)&lA[0][ar * 72 + ac * 32 + 8]  = a1;
        *(uint4*)&lA[0][ar * 72 + ac * 32 + 16] = a2;
        *(uint4*)&lA[0][ar * 72 + ac * 32 + 24] = a3;
    }
    __syncthreads();

    for (int it = 0; it < NIT; ++it) {
        const int nxt = buf ^ 1;
        uint4 a0, a1, a2, a3;
        if (it + 1 < NIT) {
            const ushort* bp = bbase + (size_t)(it + 1) * 8 * OUT_F * 8;
            glds16(bp + (size_t)(2 * w) * OUT_F * 8,     &lB[nxt][(2 * w) * 1032]);
            glds16(bp + (size_t)(2 * w + 1) * OUT_F * 8, &lB[nxt][(2 * w + 1) * 1032]);
            const ushort* ap = aptr + (it + 1) * BK;
            a0 = *(const uint4*)ap;
            a1 = *(const uint4*)(ap + 8);
            a2 = *(const uint4*)(ap + 16);
            a3 = *(const uint4*)(ap + 24);
        }
        #pragma unroll
        for (int s = 0; s < 2; ++s) {
            short8 af0 = *(short8*)&lA[buf][(w * 32 + l16) * 72 + s * 32 + quad * 8];
            short8 af1 = *(short8*)&lA[buf][(w * 32 + 16 + l16) * 72 + s * 32 + quad * 8];
            short8 bq0 = *(short8*)&lB[buf][(s * 4 + quad) * 1032 + l16 * 8];
            short8 bq1 = *(short8*)&lB[buf][(s * 4 + quad) * 1032 + (16 + l16) * 8];
            short8 bq2 = *(short8*)&lB[buf][(s * 4 + quad) * 1032 + (32 + l16) * 8];
            short8 bq3 = *(short8*)&lB[buf][(s * 4 + quad) * 1032 + (48 + l16) * 8];
            acc[0][0] = __builtin_amdgcn_mfma_f32_16x16x32_bf16(af0, bq0, acc[0][0], 0, 0, 0);
            acc[0][1] = __builtin_amdgcn_mfma_f32_16x16x32_bf16(af0, bq1, acc[0][1], 0, 0, 0);
            acc[0][2] = __builtin_amdgcn_mfma_f32_16x16x32_bf16(af0, bq2, acc[0][2], 0, 0, 0);
            acc[0][3] = __builtin_amdgcn_mfma_f32_16x16x32_bf16(af0, bq3, acc[0][3], 0, 0, 0);
            acc[1][0] = __builtin_amdgcn_mfma_f32_16x16x32_bf16(af1, bq0, acc[1][0], 0, 0, 0);
            acc[1][1] = __builtin_amdgcn_mfma_f32_16x16x32_bf16(af1, bq1, acc[1][1], 0, 0, 0);
            acc[1][2] = __builtin_amdgcn_mfma_f32_16x16x32_bf16(af1, bq2, acc[1][2], 0, 0, 0);
            acc[1][3] = __builtin_amdgcn_mfma_f32_16x16x32_bf16(af1, bq3, acc[1][3], 0, 0, 0);
        }
        if (it + 1 < NIT) {
            *(uint4*)&lA[nxt][ar * 72 + ac * 32]      = a0;
            *(uint4*)&lA[nxt][ar * 72 + ac * 32 + 8]  = a1;
            *(uint4*)&lA[nxt][ar * 72 + ac * 32 + 16] = a2;
            *(uint4*)&lA[nxt][ar * 72 + ac * 32 + 24] = a3;
        }
        __syncthreads();
        buf = nxt;
    }

    float* plane = predp + (size_t)bz * PLANE;
    #pragma unroll
    for (int fm = 0; fm < 2; fm++)
    #pragma unroll
    for (int fn = 0; fn < 4; fn++)
    #pragma unroll
    for (int r = 0; r < 4; r++) {
        int m = m0 + w * 32 + fm * 16 + quad * 4 + r;
        int n = n0 + fn * 16 + l16;
        plane[(size_t)m * OUT_F + n] = acc[fm][fn][r];
    }
}

// k_epi: 768 blocks; sums the 8 split-K planes (coherent via kernel boundary),
// squared error vs tsum, block partial -> agent atomicAdd into ctrl[0].
// RELEASE ticket; last block folds regpart and writes the 3 outputs.
// Same-address atomics only — no fences, no bulk cross-block data handoff.
__global__ __launch_bounds__(256) void k_epi(const float* __restrict__ predp,
                                             const float* __restrict__ tsum,
                                             const float* __restrict__ regpart,
                                             float* __restrict__ ctrl,
                                             float* __restrict__ out) {
    int g = blockIdx.x * 256 + threadIdx.x;     // float4 index in [0, 196608)
    int m = g / (OUT_F / 4);
    int c = g % (OUT_F / 4);
    const float4* pp = (const float4*)predp;
    float pv[4] = {0.f, 0.f, 0.f, 0.f};
    #pragma unroll
    for (int p = 0; p < SPLITK; p++) {
        float4 q = pp[g + p * PLANE4];
        pv[0] += q.x; pv[1] += q.y; pv[2] += q.z; pv[3] += q.w;
    }
    const float* ts = tsum + (size_t)m * OUTB + (size_t)c * 32;
    float lsum = 0.f;
    #pragma unroll
    for (int j = 0; j < 4; j++) {
        float4 t0 = *(const float4*)(ts + j * 8);
        float4 t1 = *(const float4*)(ts + j * 8 + 4);
        float isum = t0.x + 2.f * t0.y + 4.f * t0.z + 8.f * t0.w
                   + 16.f * t1.x + 32.f * t1.y + 64.f * t1.z - 128.f * t1.w;
        float d = pv[j] - isum;
        lsum += d * d;
    }
    float wsum = waveReduceSum(lsum);
    __shared__ float red[4];
    __shared__ int lastf;
    int lane = threadIdx.x & 63, wv = threadIdx.x >> 6;
    if (lane == 0) red[wv] = wsum;
    __syncthreads();
    if (threadIdx.x == 0) {
        atomicAdd(&ctrl[0], red[0] + red[1] + red[2] + red[3]);
        // RELEASE orders the sqsum atomic before the ticket at the coherent
        // point; k_epi has no dirty cached data so the writeback is ~free.
        u32 t = __hip_atomic_fetch_add((u32*)ctrl + 1, 1u,
                                       __ATOMIC_RELEASE, __HIP_MEMORY_SCOPE_AGENT);
        lastf = (t == (u32)(EPIBLK - 1));
    }
    __syncthreads();
    if (!lastf) return;

    float r = 0.f;
    #pragma unroll
    for (int j = 0; j < 6; j++) r += regpart[threadIdx.x + j * 256];
    r = waveReduceSum(r);
    if (lane == 0) red[wv] = r;
    __syncthreads();
    if (threadIdx.x == 0) {
        float S = atomicAdd(&ctrl[0], 0.0f);   // same-address atomic read
        float R = red[0] + red[1] + red[2] + red[3];
        float recon = S / ((float)(BATCH * OUT_F) * 255.f * 255.f);
        float reg   = 0.001f * R / (float)((size_t)IN_F * OUTB);
        out[0] = recon + reg;
        out[1] = recon;
        out[2] = reg;
    }
}

extern "C" void kernel_launch(void* const* d_in, const int* in_sizes, int n_in,
                              void* d_out, int out_size, void* d_ws, size_t ws_size,
                              hipStream_t stream) {
    const float* latent = (const float*)d_in[0];   // [1024, 4096]
    const float* tsum   = (const float*)d_in[1];   // [1024, 6144]
    const float* weight = (const float*)d_in[2];   // [4096, 6144]
    float* out      = (float*)d_out;
    float* predp    = (float*)d_ws;
    ushort* wp      = (ushort*)((char*)d_ws + WS_WP);
    ushort* labf    = (ushort*)((char*)d_ws + WS_LABF);
    float* regpart  = (float*)((char*)d_ws + WS_REGP);
    float* ctrl     = (float*)((char*)d_ws + WS_CTRL);

    k_weights<<<2048, 256, 0, stream>>>(weight, latent, wp, labf, regpart, ctrl);
    k_gemm<<<dim3(OUT_F / 64, BATCH / 128, SPLITK), 256, 0, stream>>>(labf, wp, predp);
    k_epi<<<EPIBLK, 256, 0, stream>>>(predp, tsum, regpart, ctrl, out);
}

// Round 4
// 224.731 us; speedup vs baseline: 1.5321x; 1.0300x over previous
//
#include <hip/hip_runtime.h>
#include <hip/hip_bf16.h>
#include <stdint.h>

#define IN_F   4096
#define OUT_F  768
#define OUTB   (OUT_F * 8)       // 6144
#define BATCH  1024
#define SPLITK 4
#define KSPAN  (IN_F / SPLITK)   // 1024
#define BK     64
#define NIT    (KSPAN / BK)      // 16
#define PLANE  (BATCH * OUT_F)   // 786432 floats
#define PLANE4 (PLANE / 4)       // 196608 float4
#define EPIBLK 768
#define GEMMBLK 768              // 12 n-tiles x 16 m-tiles x 4 split-K

// ws layout (bytes):
//   0        : predp   float[4][PLANE]     split-K partial planes (12.58 MB)
//   12582912 : wp      ushort[IN_F*OUT_F]  packed [(k/8)][n][k%8]  (6.29 MB)
//   18874368 : labf    ushort[BATCH*IN_F]  bf16 latent row-major   (8.39 MB)
//   27262976 : regpart float[1536]
//   27269120 : ctrl    {float sqsum; u32 ticket}   (zeroed by k_weights)
#define WS_WP    12582912
#define WS_LABF  18874368
#define WS_REGP  27262976
#define WS_CTRL  27269120

typedef short short8  __attribute__((ext_vector_type(8)));
typedef float f32x4   __attribute__((ext_vector_type(4)));
typedef unsigned int u32;

__device__ __forceinline__ ushort f2bf(float f) {
    uint32_t u = __builtin_bit_cast(uint32_t, f);
    u += 0x7FFFu + ((u >> 16) & 1u);
    return (ushort)(u >> 16);
}

__device__ __forceinline__ float waveReduceSum(float v) {
    #pragma unroll
    for (int off = 32; off > 0; off >>= 1) v += __shfl_down(v, off, 64);
    return v;
}

__device__ __forceinline__ void glds16(const void* g, void* l) {
    __builtin_amdgcn_global_load_lds(
        (const __attribute__((address_space(1))) u32*)g,
        (__attribute__((address_space(3))) u32*)l, 16, 0, 0);
}

// k_weights: blocks [0,1536): int_weights (bf16 packed [(k/8)][n][k%8]) + reg
// partials. blocks [1536,2048): latent fp32->bf16 conversion. Block 0 also
// zero-inits ctrl (workspace is poisoned between iterations).
__global__ __launch_bounds__(256) void k_weights(const float* __restrict__ w,
                                                 const float* __restrict__ latent,
                                                 ushort* __restrict__ wp,
                                                 ushort* __restrict__ labf,
                                                 float* __restrict__ regpart,
                                                 float* __restrict__ ctrl) {
    if (blockIdx.x == 0 && threadIdx.x == 0) {
        ctrl[0] = 0.f;                 // sqsum
        ((u32*)ctrl)[1] = 0u;          // ticket
    }
    if (blockIdx.x >= 1536) {
        int t = (blockIdx.x - 1536) * 256 + threadIdx.x;
        const float4* src = (const float4*)latent;
        uint4* dst = (uint4*)labf;
        #pragma unroll
        for (int j = 0; j < 4; j++) {
            int o = j * 131072 + t;
            float4 a0 = src[2 * o];
            float4 a1 = src[2 * o + 1];
            union { ushort u[8]; uint4 v; } pk;
            pk.u[0] = f2bf(a0.x); pk.u[1] = f2bf(a0.y); pk.u[2] = f2bf(a0.z); pk.u[3] = f2bf(a0.w);
            pk.u[4] = f2bf(a1.x); pk.u[5] = f2bf(a1.y); pk.u[6] = f2bf(a1.z); pk.u[7] = f2bf(a1.w);
            dst[o] = pk.v;
        }
        return;
    }

    int t  = blockIdx.x * 256 + threadIdx.x;
    int o  = t % OUT_F;
    int i8 = t / OUT_F;
    const float* src = w + (size_t)(i8 * 8) * OUTB + (size_t)o * 8;

    const float P[8] = {1.f, 2.f, 4.f, 8.f, 16.f, 32.f, 64.f, -128.f};
    float regsum = 0.f;
    union { ushort u[8]; uint4 v; } pk;

    #pragma unroll
    for (int r = 0; r < 8; r++) {
        float4 a = *(const float4*)(src + (size_t)r * OUTB);
        float4 b = *(const float4*)(src + (size_t)r * OUTB + 4);
        float x[8] = {a.x, a.y, a.z, a.w, b.x, b.y, b.z, b.w};
        float iw = 0.f;
        #pragma unroll
        for (int j = 0; j < 8; j++) {
            float p = __builtin_amdgcn_rcpf(1.f + __expf(-x[j]));
            iw += p * P[j];
            regsum += fminf(p, 1.f - p);
        }
        pk.u[r] = f2bf(iw);
    }
    *(uint4*)(wp + ((size_t)i8 * OUT_F + o) * 8) = pk.v;

    float ws = waveReduceSum(regsum);
    __shared__ float red[4];
    int lane = threadIdx.x & 63, wv = threadIdx.x >> 6;
    if (lane == 0) red[wv] = ws;
    __syncthreads();
    if (threadIdx.x == 0) regpart[blockIdx.x] = red[0] + red[1] + red[2] + red[3];
}

// k_gemm: split-K=4 bf16 MFMA GEMM, 64x64 tile, BK=64, double-buffered,
// B staged via global_load_lds; 768 blocks, 3/CU, one residency wave.
// XCD-pinned remap: XCD (d&7) owns split-K slice z=(d&7)>>1 for half the
// tiles, so its 3.5 MB k-slice working set (labf 2MB + wp 1.5MB) lives in
// its 4 MB L2 -> glds16 staging becomes L2-hit after first touch.
// Pure disjoint plane stores — NO fences/atomics.
__global__ __launch_bounds__(256) void k_gemm(const ushort* __restrict__ labf,
                                              const ushort* __restrict__ wp,
                                              float* __restrict__ predp) {
    __shared__ __align__(16) ushort lA[2][64 * 72];   // row stride 72
    __shared__ __align__(16) ushort lB[2][8 * 1032];  // plane stride 1032

    const int tid  = threadIdx.x;
    // decode XCD-pinned mapping (perf heuristic only; any mapping is correct)
    const int d  = blockIdx.x;
    const int xc = d & 7, s = d >> 3;        // xc: XCD slot, s in [0,96)
    const int bz = xc >> 1;                  // split-K slice per XCD pair
    const int tt = s + 96 * (xc & 1);        // tile index in [0,192)
    const int n0 = (tt % 12) * 64;
    const int m0 = (tt / 12) * 64;
    const int kbase = bz * KSPAN;
    const int kg0   = kbase >> 3;
    const int lane = tid & 63, w = tid >> 6;
    const int wm = w >> 1, wn = w & 1;
    const int quad = lane >> 4, l16 = lane & 15;

    f32x4 acc[2][2] = {{{0.f,0.f,0.f,0.f},{0.f,0.f,0.f,0.f}},
                       {{0.f,0.f,0.f,0.f},{0.f,0.f,0.f,0.f}}};

    const int ar = tid >> 2, ac = tid & 3;            // A: row, 16-elem k-chunk
    const ushort* aptr = labf + (size_t)(m0 + ar) * IN_F + kbase + ac * 16;
    const ushort* bbase = wp + ((size_t)kg0 * OUT_F + n0 + lane) * 8;

    int buf = 0;
    glds16(bbase + (size_t)(2 * w) * OUT_F * 8,     &lB[0][(2 * w) * 1032]);
    glds16(bbase + (size_t)(2 * w + 1) * OUT_F * 8, &lB[0][(2 * w + 1) * 1032]);
    {
        uint4 a0 = *(const uint4*)aptr;
        uint4 a1 = *(const uint4*)(aptr + 8);
        *(uint4*)&lA[0][ar * 72 + ac * 16]     = a0;
        *(uint4*)&lA[0][ar * 72 + ac * 16 + 8] = a1;
    }
    __syncthreads();

    for (int it = 0; it < NIT; ++it) {
        const int nxt = buf ^ 1;
        uint4 a0, a1;
        if (it + 1 < NIT) {
            const ushort* bp = bbase + (size_t)(it + 1) * 8 * OUT_F * 8;
            glds16(bp + (size_t)(2 * w) * OUT_F * 8,     &lB[nxt][(2 * w) * 1032]);
            glds16(bp + (size_t)(2 * w + 1) * OUT_F * 8, &lB[nxt][(2 * w + 1) * 1032]);
            a0 = *(const uint4*)(aptr + (it + 1) * BK);
            a1 = *(const uint4*)(aptr + (it + 1) * BK + 8);
        }
        #pragma unroll
        for (int ss = 0; ss < 2; ++ss) {
            short8 af0 = *(short8*)&lA[buf][(wm * 32 + l16) * 72 + ss * 32 + quad * 8];
            short8 af1 = *(short8*)&lA[buf][(wm * 32 + 16 + l16) * 72 + ss * 32 + quad * 8];
            short8 bf0 = *(short8*)&lB[buf][(ss * 4 + quad) * 1032 + (wn * 32 + l16) * 8];
            short8 bf1 = *(short8*)&lB[buf][(ss * 4 + quad) * 1032 + (wn * 32 + 16 + l16) * 8];
            acc[0][0] = __builtin_amdgcn_mfma_f32_16x16x32_bf16(af0, bf0, acc[0][0], 0, 0, 0);
            acc[0][1] = __builtin_amdgcn_mfma_f32_16x16x32_bf16(af0, bf1, acc[0][1], 0, 0, 0);
            acc[1][0] = __builtin_amdgcn_mfma_f32_16x16x32_bf16(af1, bf0, acc[1][0], 0, 0, 0);
            acc[1][1] = __builtin_amdgcn_mfma_f32_16x16x32_bf16(af1, bf1, acc[1][1], 0, 0, 0);
        }
        if (it + 1 < NIT) {
            *(uint4*)&lA[nxt][ar * 72 + ac * 16]     = a0;
            *(uint4*)&lA[nxt][ar * 72 + ac * 16 + 8] = a1;
        }
        __syncthreads();
        buf = nxt;
    }

    float* plane = predp + (size_t)bz * PLANE;
    #pragma unroll
    for (int fm = 0; fm < 2; fm++)
    #pragma unroll
    for (int fn = 0; fn < 2; fn++)
    #pragma unroll
    for (int r = 0; r < 4; r++) {
        int m = m0 + wm * 32 + fm * 16 + quad * 4 + r;
        int n = n0 + wn * 32 + fn * 16 + l16;
        plane[(size_t)m * OUT_F + n] = acc[fm][fn][r];
    }
}

// k_epi: 768 blocks; sums the 4 split-K planes (coherent via kernel boundary),
// squared error vs tsum, block partial -> agent atomicAdd into ctrl[0].
// RELEASE ticket; last block folds regpart and writes the 3 outputs.
// Same-address atomics only — no fences, no bulk cross-block data handoff.
__global__ __launch_bounds__(256) void k_epi(const float* __restrict__ predp,
                                             const float* __restrict__ tsum,
                                             const float* __restrict__ regpart,
                                             float* __restrict__ ctrl,
                                             float* __restrict__ out) {
    int g = blockIdx.x * 256 + threadIdx.x;     // float4 index in [0, 196608)
    int m = g / (OUT_F / 4);
    int c = g % (OUT_F / 4);
    const float4* pp = (const float4*)predp;
    float4 p0 = pp[g];
    float4 p1 = pp[g + PLANE4];
    float4 p2 = pp[g + 2 * PLANE4];
    float4 p3 = pp[g + 3 * PLANE4];
    float pv[4] = {p0.x + p1.x + p2.x + p3.x, p0.y + p1.y + p2.y + p3.y,
                   p0.z + p1.z + p2.z + p3.z, p0.w + p1.w + p2.w + p3.w};
    const float* ts = tsum + (size_t)m * OUTB + (size_t)c * 32;
    float lsum = 0.f;
    #pragma unroll
    for (int j = 0; j < 4; j++) {
        float4 t0 = *(const float4*)(ts + j * 8);
        float4 t1 = *(const float4*)(ts + j * 8 + 4);
        float isum = t0.x + 2.f * t0.y + 4.f * t0.z + 8.f * t0.w
                   + 16.f * t1.x + 32.f * t1.y + 64.f * t1.z - 128.f * t1.w;
        float d = pv[j] - isum;
        lsum += d * d;
    }
    float wsum = waveReduceSum(lsum);
    __shared__ float red[4];
    __shared__ int lastf;
    int lane = threadIdx.x & 63, wv = threadIdx.x >> 6;
    if (lane == 0) red[wv] = wsum;
    __syncthreads();
    if (threadIdx.x == 0) {
        atomicAdd(&ctrl[0], red[0] + red[1] + red[2] + red[3]);
        // RELEASE orders the sqsum atomic before the ticket at the coherent
        // point; same-address atomics only, no bulk-data fence needed.
        u32 t = __hip_atomic_fetch_add((u32*)ctrl + 1, 1u,
                                       __ATOMIC_RELEASE, __HIP_MEMORY_SCOPE_AGENT);
        lastf = (t == (u32)(EPIBLK - 1));
    }
    __syncthreads();
    if (!lastf) return;

    float r = 0.f;
    #pragma unroll
    for (int j = 0; j < 6; j++) r += regpart[threadIdx.x + j * 256];
    r = waveReduceSum(r);
    if (lane == 0) red[wv] = r;
    __syncthreads();
    if (threadIdx.x == 0) {
        float S = atomicAdd(&ctrl[0], 0.0f);   // same-address atomic read
        float R = red[0] + red[1] + red[2] + red[3];
        float recon = S / ((float)(BATCH * OUT_F) * 255.f * 255.f);
        float reg   = 0.001f * R / (float)((size_t)IN_F * OUTB);
        out[0] = recon + reg;
        out[1] = recon;
        out[2] = reg;
    }
}

extern "C" void kernel_launch(void* const* d_in, const int* in_sizes, int n_in,
                              void* d_out, int out_size, void* d_ws, size_t ws_size,
                              hipStream_t stream) {
    const float* latent = (const float*)d_in[0];   // [1024, 4096]
    const float* tsum   = (const float*)d_in[1];   // [1024, 6144]
    const float* weight = (const float*)d_in[2];   // [4096, 6144]
    float* out      = (float*)d_out;
    float* predp    = (float*)d_ws;
    ushort* wp      = (ushort*)((char*)d_ws + WS_WP);
    ushort* labf    = (ushort*)((char*)d_ws + WS_LABF);
    float* regpart  = (float*)((char*)d_ws + WS_REGP);
    float* ctrl     = (float*)((char*)d_ws + WS_CTRL);

    k_weights<<<2048, 256, 0, stream>>>(weight, latent, wp, labf, regpart, ctrl);
    k_gemm<<<GEMMBLK, 256, 0, stream>>>(labf, wp, predp);
    k_epi<<<EPIBLK, 256, 0, stream>>>(predp, tsum, regpart, ctrl, out);
}

// Round 5
// 199.049 us; speedup vs baseline: 1.7298x; 1.1290x over previous
//
#include <hip/hip_runtime.h>
#include <hip/hip_bf16.h>
#include <stdint.h>

#define IN_F   4096
#define OUT_F  768
#define OUTB   (OUT_F * 8)       // 6144
#define BATCH  1024
#define SPLITK 4
#define KSPAN  (IN_F / SPLITK)   // 1024
#define BK     64
#define NIT    (KSPAN / BK)      // 16
#define PLANE  (BATCH * OUT_F)   // 786432 floats
#define PLANE4 (PLANE / 4)       // 196608 float4
#define EPIBLK 768

// ws layout (bytes):
//   0        : predp   float[4][PLANE]     split-K partial planes (12.58 MB)
//   12582912 : wp      ushort[IN_F*OUT_F]  packed [(k/8)][n][k%8]  (6.29 MB)
//   18874368 : labf    ushort[BATCH*IN_F]  bf16 latent row-major   (8.39 MB)
//   27262976 : regpart float[1536]
//   27269120 : sqpart  float[768]
#define WS_WP    12582912
#define WS_LABF  18874368
#define WS_REGP  27262976
#define WS_SQP   27269120

typedef short short8  __attribute__((ext_vector_type(8)));
typedef float f32x4   __attribute__((ext_vector_type(4)));
typedef unsigned int u32;

__device__ __forceinline__ ushort f2bf(float f) {
    uint32_t u = __builtin_bit_cast(uint32_t, f);
    u += 0x7FFFu + ((u >> 16) & 1u);
    return (ushort)(u >> 16);
}

__device__ __forceinline__ float waveReduceSum(float v) {
    #pragma unroll
    for (int off = 32; off > 0; off >>= 1) v += __shfl_down(v, off, 64);
    return v;
}

__device__ __forceinline__ void glds16(const void* g, void* l) {
    __builtin_amdgcn_global_load_lds(
        (const __attribute__((address_space(1))) u32*)g,
        (__attribute__((address_space(3))) u32*)l, 16, 0, 0);
}

// k_weights: blocks [0,1536): int_weights (bf16 packed [(k/8)][n][k%8]) + reg
// partials. blocks [1536,2048): latent fp32->bf16 conversion (rides along).
__global__ __launch_bounds__(256) void k_weights(const float* __restrict__ w,
                                                 const float* __restrict__ latent,
                                                 ushort* __restrict__ wp,
                                                 ushort* __restrict__ labf,
                                                 float* __restrict__ regpart) {
    if (blockIdx.x >= 1536) {
        int t = (blockIdx.x - 1536) * 256 + threadIdx.x;
        const float4* src = (const float4*)latent;
        uint4* dst = (uint4*)labf;
        #pragma unroll
        for (int j = 0; j < 4; j++) {
            int o = j * 131072 + t;
            float4 a0 = src[2 * o];
            float4 a1 = src[2 * o + 1];
            union { ushort u[8]; uint4 v; } pk;
            pk.u[0] = f2bf(a0.x); pk.u[1] = f2bf(a0.y); pk.u[2] = f2bf(a0.z); pk.u[3] = f2bf(a0.w);
            pk.u[4] = f2bf(a1.x); pk.u[5] = f2bf(a1.y); pk.u[6] = f2bf(a1.z); pk.u[7] = f2bf(a1.w);
            dst[o] = pk.v;
        }
        return;
    }

    int t  = blockIdx.x * 256 + threadIdx.x;
    int o  = t % OUT_F;
    int i8 = t / OUT_F;
    const float* src = w + (size_t)(i8 * 8) * OUTB + (size_t)o * 8;

    const float P[8] = {1.f, 2.f, 4.f, 8.f, 16.f, 32.f, 64.f, -128.f};
    float regsum = 0.f;
    union { ushort u[8]; uint4 v; } pk;

    #pragma unroll
    for (int r = 0; r < 8; r++) {
        float4 a = *(const float4*)(src + (size_t)r * OUTB);
        float4 b = *(const float4*)(src + (size_t)r * OUTB + 4);
        float x[8] = {a.x, a.y, a.z, a.w, b.x, b.y, b.z, b.w};
        float iw = 0.f;
        #pragma unroll
        for (int j = 0; j < 8; j++) {
            float p = __builtin_amdgcn_rcpf(1.f + __expf(-x[j]));
            iw += p * P[j];
            regsum += fminf(p, 1.f - p);
        }
        pk.u[r] = f2bf(iw);
    }
    *(uint4*)(wp + ((size_t)i8 * OUT_F + o) * 8) = pk.v;

    float ws = waveReduceSum(regsum);
    __shared__ float red[4];
    int lane = threadIdx.x & 63, wv = threadIdx.x >> 6;
    if (lane == 0) red[wv] = ws;
    __syncthreads();
    if (threadIdx.x == 0) regpart[blockIdx.x] = red[0] + red[1] + red[2] + red[3];
}

// k_gemm: split-K=4 bf16 MFMA GEMM, 64x64 tile, BK=64. Triple-buffered,
// depth-2 COUNTED pipeline: A and B both staged via global_load_lds (4/iter),
// raw s_barrier + s_waitcnt vmcnt(4) so every load has 2 full iterations in
// flight — never vmcnt(0) in the main loop (T3/T4). A's LDS image is linear;
// its per-lane GLOBAL source is pre-swizzled with byte^((row&7)<<4) and the
// frag ds_reads apply the same XOR (both-sides swizzle, m173/m201) so the
// stride-128B A reads are bank-conflict-free. 768 blocks, 48 KB LDS, 3/CU.
// Pure disjoint plane stores — NO fences/atomics.
__global__ __launch_bounds__(256) void k_gemm(const ushort* __restrict__ labf,
                                              const ushort* __restrict__ wp,
                                              float* __restrict__ predp) {
    __shared__ __align__(16) ushort lA3[3][64 * 64];  // linear 64x64, XOR-swizzled image
    __shared__ __align__(16) ushort lB3[3][8 * 512];  // 8 k-group planes x 512

    const int tid  = threadIdx.x;
    const int n0   = blockIdx.x * 64;
    const int m0   = blockIdx.y * 64;
    const int bz   = blockIdx.z;
    const int kbase = bz * KSPAN;
    const int kg0   = kbase >> 3;
    const int lane = tid & 63, w = tid >> 6;
    const int wm = w >> 1, wn = w & 1;
    const int quad = lane >> 4, l16 = lane & 15;
    const int xA = (l16 & 7) << 4;                  // read-side byte XOR

    f32x4 acc[2][2] = {{{0.f,0.f,0.f,0.f},{0.f,0.f,0.f,0.f}},
                       {{0.f,0.f,0.f,0.f},{0.f,0.f,0.f,0.f}}};

    // staging: wave w owns planes p0=2w, p1=2w+1 of both A and B.
    // A plane p = rows [8p, 8p+8); lane l -> row 8p+(l>>3), col 8*((l&7)^(l>>3))
    // (source pre-swizzle matching the read-side XOR; (row&7) == l>>3).
    const int r8 = lane >> 3;
    const int c8 = (lane & 7) ^ r8;
    const int p0 = 2 * w, p1 = 2 * w + 1;
    const ushort* aSrc0 = labf + (size_t)(m0 + 8 * p0 + r8) * IN_F + kbase + 8 * c8;
    const ushort* aSrc1 = labf + (size_t)(m0 + 8 * p1 + r8) * IN_F + kbase + 8 * c8;
    const ushort* bSrc0 = wp + ((size_t)(kg0 + p0) * OUT_F + n0 + lane) * 8;
    const ushort* bSrc1 = wp + ((size_t)(kg0 + p1) * OUT_F + n0 + lane) * 8;

    #define STAGE(bi, it_) do {                                                   \
        glds16(aSrc0 + (size_t)(it_) * BK,              &lA3[bi][p0 * 512]);      \
        glds16(aSrc1 + (size_t)(it_) * BK,              &lA3[bi][p1 * 512]);      \
        glds16(bSrc0 + (size_t)(it_) * (8 * OUT_F * 8), &lB3[bi][p0 * 512]);      \
        glds16(bSrc1 + (size_t)(it_) * (8 * OUT_F * 8), &lB3[bi][p1 * 512]);      \
    } while (0)

    #define MSTEP(bi) do {                                                        \
        const char* Ab = (const char*)&lA3[bi][0];                                \
        _Pragma("unroll")                                                         \
        for (int ss = 0; ss < 2; ++ss) {                                          \
            short8 af0 = *(const short8*)(Ab + ((wm * 32 + l16) << 7)             \
                                             + ((ss * 64 + quad * 16) ^ xA));     \
            short8 af1 = *(const short8*)(Ab + ((wm * 32 + 16 + l16) << 7)        \
                                             + ((ss * 64 + quad * 16) ^ xA));     \
            short8 bf0 = *(const short8*)&lB3[bi][(ss * 4 + quad) * 512           \
                                                  + (wn * 32 + l16) * 8];         \
            short8 bf1 = *(const short8*)&lB3[bi][(ss * 4 + quad) * 512           \
                                                  + (wn * 32 + 16 + l16) * 8];    \
            acc[0][0] = __builtin_amdgcn_mfma_f32_16x16x32_bf16(af0, bf0, acc[0][0], 0, 0, 0); \
            acc[0][1] = __builtin_amdgcn_mfma_f32_16x16x32_bf16(af0, bf1, acc[0][1], 0, 0, 0); \
            acc[1][0] = __builtin_amdgcn_mfma_f32_16x16x32_bf16(af1, bf0, acc[1][0], 0, 0, 0); \
            acc[1][1] = __builtin_amdgcn_mfma_f32_16x16x32_bf16(af1, bf1, acc[1][1], 0, 0, 0); \
        }                                                                         \
    } while (0)

    // prologue: tiles 0 and 1 in flight; wait only tile 0 (own 4 loads).
    STAGE(0, 0);
    STAGE(1, 1);
    asm volatile("s_waitcnt vmcnt(4)" ::: "memory");
    __builtin_amdgcn_s_barrier();
    __builtin_amdgcn_sched_barrier(0);

    int bR = 0, bW = 2;
    for (int it = 0; it < NIT - 2; ++it) {
        STAGE(bW, it + 2);               // depth-2 prefetch
        MSTEP(bR);
        // own loads for tile it+1 done; tile it+2's 4 loads stay in flight.
        asm volatile("s_waitcnt vmcnt(4)" ::: "memory");
        __builtin_amdgcn_s_barrier();
        __builtin_amdgcn_sched_barrier(0);
        bR = (bR + 1 == 3) ? 0 : bR + 1;
        bW = (bW + 1 == 3) ? 0 : bW + 1;
    }
    // tail: it = NIT-2 (drain all), then it = NIT-1
    MSTEP(bR);
    asm volatile("s_waitcnt vmcnt(0)" ::: "memory");
    __builtin_amdgcn_s_barrier();
    __builtin_amdgcn_sched_barrier(0);
    bR = (bR + 1 == 3) ? 0 : bR + 1;
    MSTEP(bR);

    #undef STAGE
    #undef MSTEP

    float* plane = predp + (size_t)bz * PLANE;
    #pragma unroll
    for (int fm = 0; fm < 2; fm++)
    #pragma unroll
    for (int fn = 0; fn < 2; fn++)
    #pragma unroll
    for (int r = 0; r < 4; r++) {
        int m = m0 + wm * 32 + fm * 16 + quad * 4 + r;
        int n = n0 + wn * 32 + fn * 16 + l16;
        plane[(size_t)m * OUT_F + n] = acc[fm][fn][r];
    }
}

// k_epi: 768 blocks x 256 threads; thread -> 4 consecutive n (one float4 per
// plane, 128B contiguous tsum). Per-block partial -> plain store. NO atomics.
__global__ __launch_bounds__(256) void k_epi(const float* __restrict__ predp,
                                             const float* __restrict__ tsum,
                                             float* __restrict__ sqpart) {
    int g = blockIdx.x * 256 + threadIdx.x;     // float4 index in [0, 196608)
    int m = g / (OUT_F / 4);
    int c = g % (OUT_F / 4);
    const float4* pp = (const float4*)predp;
    float4 p0 = pp[g];
    float4 p1 = pp[g + PLANE4];
    float4 p2 = pp[g + 2 * PLANE4];
    float4 p3 = pp[g + 3 * PLANE4];
    float pv[4] = {p0.x + p1.x + p2.x + p3.x, p0.y + p1.y + p2.y + p3.y,
                   p0.z + p1.z + p2.z + p3.z, p0.w + p1.w + p2.w + p3.w};
    const float* ts = tsum + (size_t)m * OUTB + (size_t)c * 32;
    float lsum = 0.f;
    #pragma unroll
    for (int j = 0; j < 4; j++) {
        float4 t0 = *(const float4*)(ts + j * 8);
        float4 t1 = *(const float4*)(ts + j * 8 + 4);
        float isum = t0.x + 2.f * t0.y + 4.f * t0.z + 8.f * t0.w
                   + 16.f * t1.x + 32.f * t1.y + 64.f * t1.z - 128.f * t1.w;
        float d = pv[j] - isum;
        lsum += d * d;
    }
    float wsum = waveReduceSum(lsum);
    __shared__ float red[4];
    if ((threadIdx.x & 63) == 0) red[threadIdx.x >> 6] = wsum;
    __syncthreads();
    if (threadIdx.x == 0)
        sqpart[blockIdx.x] = red[0] + red[1] + red[2] + red[3];
}

// k_fin: 1 block; reduce regpart[1536] + sqpart[768], write the 3 outputs.
__global__ __launch_bounds__(256) void k_fin(const float* __restrict__ regpart,
                                             const float* __restrict__ sqpart,
                                             float* __restrict__ out) {
    int tid = threadIdx.x;
    float r = 0.f, s = 0.f;
    #pragma unroll
    for (int j = 0; j < 6; j++) r += regpart[tid + j * 256];
    #pragma unroll
    for (int j = 0; j < 3; j++) s += sqpart[tid + j * 256];
    r = waveReduceSum(r);
    s = waveReduceSum(s);
    __shared__ float redR[4], redS[4];
    int lane = tid & 63, wv = tid >> 6;
    if (lane == 0) { redR[wv] = r; redS[wv] = s; }
    __syncthreads();
    if (tid == 0) {
        float R = redR[0] + redR[1] + redR[2] + redR[3];
        float S = redS[0] + redS[1] + redS[2] + redS[3];
        float recon = S / ((float)(BATCH * OUT_F) * 255.f * 255.f);
        float reg   = 0.001f * R / (float)((size_t)IN_F * OUTB);
        out[0] = recon + reg;
        out[1] = recon;
        out[2] = reg;
    }
}

extern "C" void kernel_launch(void* const* d_in, const int* in_sizes, int n_in,
                              void* d_out, int out_size, void* d_ws, size_t ws_size,
                              hipStream_t stream) {
    const float* latent = (const float*)d_in[0];   // [1024, 4096]
    const float* tsum   = (const float*)d_in[1];   // [1024, 6144]
    const float* weight = (const float*)d_in[2];   // [4096, 6144]
    float* out      = (float*)d_out;
    float* predp    = (float*)d_ws;
    ushort* wp      = (ushort*)((char*)d_ws + WS_WP);
    ushort* labf    = (ushort*)((char*)d_ws + WS_LABF);
    float* regpart  = (float*)((char*)d_ws + WS_REGP);
    float* sqpart   = (float*)((char*)d_ws + WS_SQP);

    k_weights<<<2048, 256, 0, stream>>>(weight, latent, wp, labf, regpart);
    k_gemm<<<dim3(OUT_F / 64, BATCH / 64, SPLITK), 256, 0, stream>>>(labf, wp, predp);
    k_epi<<<EPIBLK, 256, 0, stream>>>(predp, tsum, sqpart);
    k_fin<<<1, 256, 0, stream>>>(regpart, sqpart, out);
}